// Round 6
// baseline (15897.456 us; speedup 1.0000x reference)
//
#include <hip/hip_runtime.h>
#include <cstdint>

// HardLSTM: T=512 B=32 I=512 H=1024, 2 layers, bidirectional.
// cvt(fp32->fp16) -> GEMM gx0 -> persistent recur L0 -> GEMM gx1 -> recur L1.
// Recurrence handshake: tag-embedded 16B chunks [tag, 4 x fp16 h, tag] via
// sc0|sc1 (coherent-at-L3) stores, fire-and-forget. Consumers' stage load IS
// the poll (retry until tags == t+1). Double-buffer by parity + monotone tags.
// No flags, no producer ack, 2 lgkm-only barriers per step.

typedef _Float16 half8 __attribute__((ext_vector_type(8)));
typedef _Float16 half4v __attribute__((ext_vector_type(4)));
typedef float floatx4 __attribute__((ext_vector_type(4)));
typedef int int4v __attribute__((ext_vector_type(4)));
typedef int int2v __attribute__((ext_vector_type(2)));

#define T_LEN 512
#define BATCH 32
#define HID 1024
#define NTB 16384   // T*B
#define UPW 16      // hidden units per WG
#define WPD 64      // WGs per direction
#define CHUNKS_DIR 8192       // WPD*128 chunks per (dir,parity)

__device__ __forceinline__ float hsig(float x) {
  return fminf(fmaxf(fmaf(0.2f, x, 0.5f), 0.0f), 1.0f);
}
__device__ __forceinline__ float htanh(float x) {
  return fminf(fmaxf(x, -1.0f), 1.0f);
}

__device__ __forceinline__ int4v load_co16(const void* p) {
  int4v r;
  asm volatile("global_load_dwordx4 %0, %1, off sc0 sc1"
               : "=&v"(r) : "v"(p) : "memory");
  return r;
}
__device__ __forceinline__ void store_co16(void* p, int4v v) {
  asm volatile("global_store_dwordx4 %0, %1, off sc0 sc1"
               :: "v"(p), "v"(v) : "memory");
}
__device__ __forceinline__ void waitcnt0() {
  asm volatile("s_waitcnt vmcnt(0)" ::: "memory");
}
// barrier with LDS-visibility only (no vmcnt drain)
__device__ __forceinline__ void barrier_lgkm() {
  asm volatile("s_waitcnt lgkmcnt(0)" ::: "memory");
  __builtin_amdgcn_sched_barrier(0);
  __builtin_amdgcn_s_barrier();
  __builtin_amdgcn_sched_barrier(0);
}

__device__ __forceinline__ void gll16(const void* g, void* l) {
  __builtin_amdgcn_global_load_lds((const __attribute__((address_space(1))) void*)g,
                                   (__attribute__((address_space(3))) void*)l,
                                   16, 0, 0);
}

// 4x4 transpose across fk lane-groups: v[r] = (gate fk, unit r, batch fr)
// -> lane gets all 4 gates of unit fk. (proven r3/r5)
__device__ __forceinline__ void gate_xpose(floatx4 v, bool i1, bool i0,
                                           float& gI, float& gF,
                                           float& gG, float& gO) {
  float s0 = i1 ? v[0] : v[2], s1 = i1 ? v[1] : v[3];
  float r0 = __shfl_xor(s0, 32), r1 = __shfl_xor(s1, 32);
  float A0 = i1 ? r0 : v[0], A1 = i1 ? r1 : v[1];
  float A2 = i1 ? v[2] : r0, A3 = i1 ? v[3] : r1;
  s0 = i0 ? A0 : A1; s1 = i0 ? A2 : A3;
  r0 = __shfl_xor(s0, 16); r1 = __shfl_xor(s1, 16);
  gI = i0 ? r0 : A0; gF = i0 ? A1 : r0;
  gG = i0 ? r1 : A2; gO = i0 ? A3 : r1;
}

// pack 4 fk-lanes' fp16 h into one chunk, store from fk==0 lanes.
// chunk layout: [tag, {h(fk0),h(fk1)}, {h(fk2),h(fk3)}, tag]
__device__ __forceinline__ void publish_h(float h, int tag, char* cb,
                                          int wgd, int w, int fr, int fk) {
  union { _Float16 f; unsigned short u; } cv; cv.f = (_Float16)h;
  int hb = (int)cv.u;
  int p = __shfl_xor(hb, 16);  // partner fk^1
  int d01 = (fk & 1) ? ((p & 0xffff) | (hb << 16))
                     : ((hb & 0xffff) | (p << 16));
  int d23 = __shfl_xor(d01, 32);  // fk0 <- pair of fk2
  if (fk == 0) {
    int4v v = {tag, d01, d23, tag};
    store_co16(cb + (size_t)(wgd * 128 + w * 16 + fr) * 16, v);
  }
}

__global__ __launch_bounds__(256) void cvt_f32_f16(const float* __restrict__ s,
                                                   _Float16* __restrict__ d,
                                                   int n4) {
  int i = blockIdx.x * blockDim.x + threadIdx.x;
  int stride = gridDim.x * blockDim.x;
  for (; i < n4; i += stride) {
    float4 v = ((const float4*)s)[i];
    half4v h = {(_Float16)v.x, (_Float16)v.y, (_Float16)v.z, (_Float16)v.w};
    ((half4v*)d)[i] = h;
  }
}

// C[M=8192][NTB] = A[M][K] * B[NTB][K]^T + bias[M], fp16 out. (unchanged)
__global__ __launch_bounds__(256) void gemm_gx(const _Float16* __restrict__ A,
                                               const _Float16* __restrict__ B,
                                               const float* __restrict__ bias,
                                               _Float16* __restrict__ C,
                                               int K) {
  __shared__ __align__(16) _Float16 A_s[128 * 64];
  __shared__ __align__(16) _Float16 B_s[128 * 64];
  const int tid = threadIdx.x;
  const int lane = tid & 63;
  const int w = tid >> 6;
  const int bm = blockIdx.x >> 7;
  const int bn = blockIdx.x & 127;
  const int m0 = bm * 128, n0 = bn * 128;

  floatx4 acc[4][4] = {};

  const int srow = w * 8 + (lane >> 3);
  const int scol = ((lane & 7) ^ ((lane >> 3) & 7)) * 8;
  const _Float16* Ag = A + (size_t)(m0 + srow) * K + scol;
  const _Float16* Bg = B + (size_t)(n0 + srow) * K + scol;
  char* As_base = (char*)A_s + (size_t)(w * 8) * 128;
  char* Bs_base = (char*)B_s + (size_t)(w * 8) * 128;

  const int wm = (w >> 1) * 64;
  const int wn = (w & 1) * 64;
  const int fr = lane & 15;
  const int fk = lane >> 4;

  for (int kb = 0; kb < K; kb += 64) {
#pragma unroll
    for (int i = 0; i < 4; ++i) {
      gll16(Ag + (size_t)i * 32 * K + kb, As_base + i * 32 * 128);
      gll16(Bg + (size_t)i * 32 * K + kb, Bs_base + i * 32 * 128);
    }
    __syncthreads();
#pragma unroll
    for (int kt = 0; kt < 2; ++kt) {
      half8 af[4], bf[4];
#pragma unroll
      for (int mi = 0; mi < 4; ++mi) {
        int row = wm + mi * 16 + fr;
        int k8 = kt * 4 + fk;
        af[mi] = *(const half8*)(A_s + row * 64 + ((k8 ^ (row & 7)) << 3));
      }
#pragma unroll
      for (int ni = 0; ni < 4; ++ni) {
        int row = wn + ni * 16 + fr;
        int k8 = kt * 4 + fk;
        bf[ni] = *(const half8*)(B_s + row * 64 + ((k8 ^ (row & 7)) << 3));
      }
#pragma unroll
      for (int mi = 0; mi < 4; ++mi)
#pragma unroll
        for (int ni = 0; ni < 4; ++ni)
          acc[mi][ni] = __builtin_amdgcn_mfma_f32_16x16x32_f16(af[mi], bf[ni],
                                                               acc[mi][ni], 0, 0, 0);
    }
    __syncthreads();
  }

#pragma unroll
  for (int mi = 0; mi < 4; ++mi) {
    int rowb = m0 + wm + mi * 16 + fk * 4;
#pragma unroll
    for (int r = 0; r < 4; ++r) {
      float bv = bias[rowb + r];
#pragma unroll
      for (int ni = 0; ni < 4; ++ni) {
        int col = n0 + wn + ni * 16 + fr;
        C[(size_t)(rowb + r) * NTB + col] = (_Float16)(acc[mi][ni][r] + bv);
      }
    }
  }
}

// Persistent bidirectional recurrence. Grid = 128 WGs x 512 thr.
// chunkbuf: per (dir,parity) 8192 chunks of 16B. Chunk G: producer wgd=G>>7,
// c=G&127 -> wave w=c>>4 (wu=w>>1, wn=w&1), fr=c&15 -> bat=wn*16+fr,
// units u0+wu*4+{0..3}.
__global__ __launch_bounds__(512) void recur(const _Float16* __restrict__ gx,
                                             const _Float16* __restrict__ whh,
                                             const float* __restrict__ h0,
                                             const float* __restrict__ c0,
                                             char* __restrict__ chunkbuf,
                                             int layer,
                                             _Float16* __restrict__ yf16,
                                             float* __restrict__ yf32,
                                             float* __restrict__ hn,
                                             float* __restrict__ cn) {
  __shared__ __align__(16) _Float16 h_s[BATCH * HID];  // 64KB swizzled [b][k]

  const int tid = threadIdx.x;
  const int lane = tid & 63;
  const int w = tid >> 6;
  const int wu = w >> 1, wn = w & 1;
  const int dir = blockIdx.x >> 6;
  const int wgd = blockIdx.x & 63;
  const int u0 = wgd * UPW;
  const int fr = lane & 15, fk = lane >> 4;

  char* cb0 = chunkbuf + (size_t)(dir * 2 + 0) * CHUNKS_DIR * 16;
  char* cb1 = chunkbuf + (size_t)(dir * 2 + 1) * CHUNKS_DIR * 16;

  // A fragments: lane supplies row fr -> gate g=fr>>2, unit offset du=fr&3
  half8 af[32];
  {
    const int g = fr >> 2, du = fr & 3;
    const _Float16* wrow = whh + ((size_t)dir * 4096 + g * 1024 + u0 + wu * 4 + du) * HID;
#pragma unroll
    for (int kt = 0; kt < 32; ++kt)
      af[kt] = *(const half8*)(wrow + kt * 32 + fk * 8);
  }

  const int unit = u0 + wu * 4 + fk;   // this lane's unit (post-transpose)
  const int bat  = wn * 16 + fr;       // this lane's batch
  const size_t st0 = (size_t)(layer * 2 + dir) * (BATCH * HID);
  float c = c0[st0 + (size_t)bat * HID + unit];

  // init: publish h0 with tag 1 into parity-0 buffer (fire-and-forget)
  publish_h(h0[st0 + (size_t)bat * HID + unit], 1, cb0, wgd, w, fr, fk);

  const size_t GS = (size_t)1024 * NTB;
  const _Float16* gxp = gx + ((size_t)dir * 4096 + unit) * NTB;

  // preload gx for t=0
  int ts0 = dir ? (T_LEN - 1) : 0;
  float gxi = (float)gxp[0 * GS + (size_t)ts0 * BATCH + bat];
  float gxf = (float)gxp[1 * GS + (size_t)ts0 * BATCH + bat];
  float gxg = (float)gxp[2 * GS + (size_t)ts0 * BATCH + bat];
  float gxo = (float)gxp[3 * GS + (size_t)ts0 * BATCH + bat];

  const bool i1 = (fk >> 1) & 1, i0 = fk & 1;

  for (int t = 0; t < T_LEN; ++t) {
    const int want = t + 1;
    const char* src = ((t & 1) ? cb1 : cb0) + (size_t)tid * 256;

    // stage h(t-1): the load IS the poll. 16 chunks/thread, all outstanding.
    int4v val[16];
    for (;;) {
#pragma unroll
      for (int i = 0; i < 16; ++i) val[i] = load_co16(src + i * 16);
      waitcnt0();
      bool ok = true;
#pragma unroll
      for (int i = 0; i < 16; ++i)
        ok &= (val[i][0] == want) & (val[i][3] == want);
      if (ok) break;
      __builtin_amdgcn_s_sleep(2);
    }
    // scatter payloads to swizzled LDS: chunk -> (bat2, 16B slot, 8B half)
#pragma unroll
    for (int i = 0; i < 16; ++i) {
      int G = tid * 16 + i;
      int wg2 = G >> 7, cc = G & 127;
      int bat2 = ((cc >> 4) & 1) * 16 + (cc & 15);
      int uh = cc >> 5;
      int slot = wg2 * 2 + (uh >> 1);
      int lds_b = bat2 * 2048 + ((slot * 16) ^ ((bat2 & 7) << 4)) + (uh & 1) * 8;
      *(int2v*)((char*)h_s + lds_b) = (int2v){val[i][1], val[i][2]};
    }

    // prefetch gx(t+1): latency hides under MFMA + next poll
    int tn = (t + 1 < T_LEN) ? t + 1 : t;
    int tsn = dir ? (T_LEN - 1 - tn) : tn;
    float ngxi = (float)gxp[0 * GS + (size_t)tsn * BATCH + bat];
    float ngxf = (float)gxp[1 * GS + (size_t)tsn * BATCH + bat];
    float ngxg = (float)gxp[2 * GS + (size_t)tsn * BATCH + bat];
    float ngxo = (float)gxp[3 * GS + (size_t)tsn * BATCH + bat];

    barrier_lgkm();  // h_s ready (no vmcnt drain)

    // MFMA: 16 rows (4 gates x 4 units) x 16 batch x K=1024, two chains
    floatx4 acc0 = {0.f, 0.f, 0.f, 0.f}, acc1 = {0.f, 0.f, 0.f, 0.f};
    {
      const char* hp = (const char*)h_s + bat * 2048;
      const int bx = (bat & 7) << 4;
#pragma unroll
      for (int kt = 0; kt < 32; kt += 2) {
        half8 b0 = *(const half8*)(hp + ((kt * 64 + fk * 16) ^ bx));
        half8 b1 = *(const half8*)(hp + (((kt + 1) * 64 + fk * 16) ^ bx));
        acc0 = __builtin_amdgcn_mfma_f32_16x16x32_f16(af[kt], b0, acc0, 0, 0, 0);
        acc1 = __builtin_amdgcn_mfma_f32_16x16x32_f16(af[kt + 1], b1, acc1, 0, 0, 0);
      }
    }
    floatx4 v = acc0 + acc1;

    float gI, gF, gG, gO;
    gate_xpose(v, i1, i0, gI, gF, gG, gO);

    float ig = hsig(gI + gxi);
    float fg = hsig(gF + gxf);
    float gg = htanh(gG + gxg);
    float og = hsig(gO + gxo);
    c = fg * c + ig * gg;
    float h = og * htanh(c);

    const int tseq = dir ? (T_LEN - 1 - t) : t;
    size_t yidx = ((size_t)tseq * BATCH + bat) * 2048 + (size_t)dir * 1024 + unit;
    if (yf16) yf16[yidx] = (_Float16)h;
    else      yf32[yidx] = h;

    gxi = ngxi; gxf = ngxf; gxg = ngxg; gxo = ngxo;

    if (t == T_LEN - 1) {
      size_t o = st0 + (size_t)bat * HID + unit;
      hn[o] = h;
      cn[o] = c;
    } else {
      // publish h(t) with tag t+2 into parity (t+1)&1 (fire-and-forget)
      publish_h(h, t + 2, ((t + 1) & 1) ? cb1 : cb0, wgd, w, fr, fk);
    }

    barrier_lgkm();  // all h_s reads done before next step's ds_writes
  }
}

extern "C" void kernel_launch(void* const* d_in, const int* in_sizes, int n_in,
                              void* d_out, int out_size, void* d_ws, size_t ws_size,
                              hipStream_t stream) {
  const float* x    = (const float*)d_in[0];
  const float* h0   = (const float*)d_in[1];
  const float* c0   = (const float*)d_in[2];
  const float* wih0 = (const float*)d_in[3];
  const float* whh0 = (const float*)d_in[4];
  const float* b0   = (const float*)d_in[5];
  const float* wih1 = (const float*)d_in[6];
  const float* whh1 = (const float*)d_in[7];
  const float* b1   = (const float*)d_in[8];
  float* out = (float*)d_out;

  char* ws = (char*)d_ws;
  size_t off = 0;
  char* chunkbuf = ws;                        off += (size_t)2 * 2 * 2 * CHUNKS_DIR * 16;  // 1MB
  _Float16* xh    = (_Float16*)(ws + off);    off += (size_t)8388608 * 2;
  _Float16* wih0h = (_Float16*)(ws + off);    off += (size_t)4194304 * 2;
  _Float16* whh0h = (_Float16*)(ws + off);    off += (size_t)8388608 * 2;
  _Float16* wih1h = (_Float16*)(ws + off);    off += (size_t)16777216 * 2;
  _Float16* whh1h = (_Float16*)(ws + off);    off += (size_t)8388608 * 2;
  _Float16* y0h   = (_Float16*)(ws + off);    off += (size_t)33554432 * 2;
  _Float16* gxbuf = (_Float16*)(ws + off);    off += (size_t)134217728 * 2;

  hipMemsetAsync(chunkbuf, 0, (size_t)2 * 2 * 2 * CHUNKS_DIR * 16, stream);

  cvt_f32_f16<<<2048, 256, 0, stream>>>(x,    xh,    8388608 / 4);
  cvt_f32_f16<<<2048, 256, 0, stream>>>(wih0, wih0h, 4194304 / 4);
  cvt_f32_f16<<<2048, 256, 0, stream>>>(whh0, whh0h, 8388608 / 4);
  cvt_f32_f16<<<2048, 256, 0, stream>>>(wih1, wih1h, 16777216 / 4);
  cvt_f32_f16<<<2048, 256, 0, stream>>>(whh1, whh1h, 8388608 / 4);

  float* hn = out + 33554432;
  float* cn = out + 33685504;

  char* cb_l0 = chunkbuf;
  char* cb_l1 = chunkbuf + (size_t)2 * 2 * CHUNKS_DIR * 16;

  // layer 0
  gemm_gx<<<8192, 256, 0, stream>>>(wih0h, xh, b0, gxbuf, 512);
  recur<<<128, 512, 0, stream>>>(gxbuf, whh0h, h0, c0, cb_l0, 0,
                                 y0h, nullptr, hn, cn);
  // layer 1
  gemm_gx<<<8192, 256, 0, stream>>>(wih1h, y0h, b1, gxbuf, 2048);
  recur<<<128, 512, 0, stream>>>(gxbuf, whh1h, h0, c0, cb_l1, 1,
                                 nullptr, out, hn, cn);
}

// Round 8
// 6016.313 us; speedup vs baseline: 2.6424x; 2.6424x over previous
//
#include <hip/hip_runtime.h>
#include <cstdint>

// HardLSTM: T=512 B=32 I=512 H=1024, 2 layers, bidirectional.
// cvt(fp32->fp16) -> GEMM gx0 -> persistent recur L0 -> GEMM gx1 -> recur L1.
// Recurrence (r5 protocol, proven): h via sc0|sc1 (coherent-at-L3) accesses,
// per-WG flag array, wave0 polls, lgkm-only barriers, gx prefetch.
// NEW r8: h transported as u8 fixed-point (q = rint(127h)+128) -> staged
// bytes halved. Dequant: B' = fp16(0x6400|u8) = 1024+u8 via v_perm; weights
// pre-scaled by 1/127; constant 1152*rowsum(w') folded into accumulator init.
// __launch_bounds__(512,2): 256-VGPR budget so af[32] (128 VGPR) is resident.

typedef _Float16 half8 __attribute__((ext_vector_type(8)));
typedef _Float16 half4v __attribute__((ext_vector_type(4)));
typedef float floatx4 __attribute__((ext_vector_type(4)));
typedef int int4v __attribute__((ext_vector_type(4)));
typedef int int2v __attribute__((ext_vector_type(2)));

#define T_LEN 512
#define BATCH 32
#define HID 1024
#define NTB 16384   // T*B
#define UPW 16      // hidden units per WG
#define WPD 64      // WGs per direction

__device__ __forceinline__ float hsig(float x) {
  return fminf(fmaxf(fmaf(0.2f, x, 0.5f), 0.0f), 1.0f);
}
__device__ __forceinline__ float htanh(float x) {
  return fminf(fmaxf(x, -1.0f), 1.0f);
}

__device__ __forceinline__ int4v load_co16(const void* p) {
  int4v r;
  asm volatile("global_load_dwordx4 %0, %1, off sc0 sc1"
               : "=&v"(r) : "v"(p) : "memory");
  return r;
}
__device__ __forceinline__ void store_co8(void* p, int2v v) {
  asm volatile("global_store_dwordx2 %0, %1, off sc0 sc1"
               :: "v"(p), "v"(v) : "memory");
}
__device__ __forceinline__ void waitcnt0() {
  asm volatile("s_waitcnt vmcnt(0)" ::: "memory");
}
// barrier with LDS-visibility only (no vmcnt drain)
__device__ __forceinline__ void barrier_lgkm() {
  asm volatile("s_waitcnt lgkmcnt(0)" ::: "memory");
  __builtin_amdgcn_sched_barrier(0);
  __builtin_amdgcn_s_barrier();
  __builtin_amdgcn_sched_barrier(0);
}

__device__ __forceinline__ void gll16(const void* g, void* l) {
  __builtin_amdgcn_global_load_lds((const __attribute__((address_space(1))) void*)g,
                                   (__attribute__((address_space(3))) void*)l,
                                   16, 0, 0);
}

// 4x4 transpose across fk lane-groups (proven r3/r5)
__device__ __forceinline__ void gate_xpose(floatx4 v, bool i1, bool i0,
                                           float& gI, float& gF,
                                           float& gG, float& gO) {
  float s0 = i1 ? v[0] : v[2], s1 = i1 ? v[1] : v[3];
  float r0 = __shfl_xor(s0, 32), r1 = __shfl_xor(s1, 32);
  float A0 = i1 ? r0 : v[0], A1 = i1 ? r1 : v[1];
  float A2 = i1 ? v[2] : r0, A3 = i1 ? v[3] : r1;
  s0 = i0 ? A0 : A1; s1 = i0 ? A2 : A3;
  r0 = __shfl_xor(s0, 16); r1 = __shfl_xor(s1, 16);
  gI = i0 ? r0 : A0; gF = i0 ? A1 : r0;
  gG = i0 ? r1 : A2; gO = i0 ? A3 : r1;
}

__global__ __launch_bounds__(256) void cvt_f32_f16(const float* __restrict__ s,
                                                   _Float16* __restrict__ d,
                                                   int n4) {
  int i = blockIdx.x * blockDim.x + threadIdx.x;
  int stride = gridDim.x * blockDim.x;
  for (; i < n4; i += stride) {
    float4 v = ((const float4*)s)[i];
    half4v h = {(_Float16)v.x, (_Float16)v.y, (_Float16)v.z, (_Float16)v.w};
    ((half4v*)d)[i] = h;
  }
}

// C[M=8192][NTB] = A[M][K] * B[NTB][K]^T + bias[M], fp16 out. (unchanged)
__global__ __launch_bounds__(256) void gemm_gx(const _Float16* __restrict__ A,
                                               const _Float16* __restrict__ B,
                                               const float* __restrict__ bias,
                                               _Float16* __restrict__ C,
                                               int K) {
  __shared__ __align__(16) _Float16 A_s[128 * 64];
  __shared__ __align__(16) _Float16 B_s[128 * 64];
  const int tid = threadIdx.x;
  const int lane = tid & 63;
  const int w = tid >> 6;
  const int bm = blockIdx.x >> 7;
  const int bn = blockIdx.x & 127;
  const int m0 = bm * 128, n0 = bn * 128;

  floatx4 acc[4][4] = {};

  const int srow = w * 8 + (lane >> 3);
  const int scol = ((lane & 7) ^ ((lane >> 3) & 7)) * 8;
  const _Float16* Ag = A + (size_t)(m0 + srow) * K + scol;
  const _Float16* Bg = B + (size_t)(n0 + srow) * K + scol;
  char* As_base = (char*)A_s + (size_t)(w * 8) * 128;
  char* Bs_base = (char*)B_s + (size_t)(w * 8) * 128;

  const int wm = (w >> 1) * 64;
  const int wn = (w & 1) * 64;
  const int fr = lane & 15;
  const int fk = lane >> 4;

  for (int kb = 0; kb < K; kb += 64) {
#pragma unroll
    for (int i = 0; i < 4; ++i) {
      gll16(Ag + (size_t)i * 32 * K + kb, As_base + i * 32 * 128);
      gll16(Bg + (size_t)i * 32 * K + kb, Bs_base + i * 32 * 128);
    }
    __syncthreads();
#pragma unroll
    for (int kt = 0; kt < 2; ++kt) {
      half8 af[4], bf[4];
#pragma unroll
      for (int mi = 0; mi < 4; ++mi) {
        int row = wm + mi * 16 + fr;
        int k8 = kt * 4 + fk;
        af[mi] = *(const half8*)(A_s + row * 64 + ((k8 ^ (row & 7)) << 3));
      }
#pragma unroll
      for (int ni = 0; ni < 4; ++ni) {
        int row = wn + ni * 16 + fr;
        int k8 = kt * 4 + fk;
        bf[ni] = *(const half8*)(B_s + row * 64 + ((k8 ^ (row & 7)) << 3));
      }
#pragma unroll
      for (int mi = 0; mi < 4; ++mi)
#pragma unroll
        for (int ni = 0; ni < 4; ++ni)
          acc[mi][ni] = __builtin_amdgcn_mfma_f32_16x16x32_f16(af[mi], bf[ni],
                                                               acc[mi][ni], 0, 0, 0);
    }
    __syncthreads();
  }

#pragma unroll
  for (int mi = 0; mi < 4; ++mi) {
    int rowb = m0 + wm + mi * 16 + fk * 4;
#pragma unroll
    for (int r = 0; r < 4; ++r) {
      float bv = bias[rowb + r];
#pragma unroll
      for (int ni = 0; ni < 4; ++ni) {
        int col = n0 + wn + ni * 16 + fr;
        C[(size_t)(rowb + r) * NTB + col] = (_Float16)(acc[mi][ni][r] + bv);
      }
    }
  }
}

// Persistent bidirectional recurrence. Grid = 128 WGs x 512 thr.
// Wave w = (wu = w>>1, wn = w&1): A rows = 4 gates x 4 units, batch half wn.
// h transported as u8; LDS holds B' = 1024+u8 in fp16.
__global__ __launch_bounds__(512, 2) void recur(const _Float16* __restrict__ gx,
                                                const _Float16* __restrict__ whh,
                                                const float* __restrict__ h0,
                                                const float* __restrict__ c0,
                                                unsigned char* __restrict__ hbuf,
                                                int* __restrict__ flags,
                                                int layer,
                                                _Float16* __restrict__ yf16,
                                                float* __restrict__ yf32,
                                                float* __restrict__ hn,
                                                float* __restrict__ cn) {
  __shared__ __align__(16) _Float16 h_s[BATCH * HID];        // 64KB swizzled [b][k]
  __shared__ __align__(16) unsigned char hout_s[BATCH * UPW]; // 512B

  const int tid = threadIdx.x;
  const int lane = tid & 63;
  const int w = tid >> 6;
  const int wu = w >> 1, wn = w & 1;
  const int dir = blockIdx.x >> 6;
  const int wgd = blockIdx.x & 63;
  const int u0 = wgd * UPW;
  const int fr = lane & 15, fk = lane >> 4;

  // A fragments scaled by 1/127; rowsum for the 1152-offset correction.
  half8 af[32];
  float rowsum = 0.f;
  {
    const int g = fr >> 2, du = fr & 3;
    const _Float16* wrow = whh + ((size_t)dir * 4096 + g * 1024 + u0 + wu * 4 + du) * HID;
#pragma unroll
    for (int kt = 0; kt < 32; ++kt) {
      half8 raw = *(const half8*)(wrow + kt * 32 + fk * 8);
      half8 s;
#pragma unroll
      for (int e = 0; e < 8; ++e) {
        float v = (float)raw[e] * (1.f / 127.f);
        s[e] = (_Float16)v;
        rowsum += (float)s[e];
      }
      af[kt] = s;
    }
  }
  rowsum += __shfl_xor(rowsum, 16);
  rowsum += __shfl_xor(rowsum, 32);     // full row sum of row fr, all lanes
  float corr0 = 1152.f * __shfl(rowsum, fk * 4 + 0);
  float corr1 = 1152.f * __shfl(rowsum, fk * 4 + 1);
  float corr2 = 1152.f * __shfl(rowsum, fk * 4 + 2);
  float corr3 = 1152.f * __shfl(rowsum, fk * 4 + 3);

  const int unit = u0 + wu * 4 + fk;   // this lane's unit (post-transpose)
  const int bat  = wn * 16 + fr;       // this lane's batch
  const size_t st0 = (size_t)(layer * 2 + dir) * (BATCH * HID);
  float c = c0[st0 + (size_t)bat * HID + unit];

  unsigned char* buf0 = hbuf + (size_t)dir * 32768;
  unsigned char* buf1 = hbuf + (size_t)(2 + dir) * 32768;
  int* fl = flags + dir * WPD;

  // init: quantize h0 slice, publish into parity-0, flag=1 (r5 protocol)
  {
    float hv0 = h0[st0 + (size_t)bat * HID + unit];
    int q = (int)rintf(fminf(fmaxf(hv0, -1.f), 1.f) * 127.f) + 128;
    hout_s[bat * UPW + wu * 4 + fk] = (unsigned char)q;
  }
  __syncthreads();
  if (w == 0) {
    int b = lane >> 1, hf = lane & 1;
    int2v v2 = *(const int2v*)(hout_s + lane * 8);
    store_co8(buf0 + (size_t)b * HID + u0 + hf * 8, v2);
    waitcnt0();
    if (lane == 0) {
      int fv = 1;
      asm volatile("global_store_dword %0, %1, off sc0 sc1"
                   :: "v"(fl + wgd), "v"(fv) : "memory");
    }
  }

  const size_t GS = (size_t)1024 * NTB;
  const _Float16* gxp = gx + ((size_t)dir * 4096 + unit) * NTB;

  // preload gx for t=0
  int ts0 = dir ? (T_LEN - 1) : 0;
  float gxi = (float)gxp[0 * GS + (size_t)ts0 * BATCH + bat];
  float gxf = (float)gxp[1 * GS + (size_t)ts0 * BATCH + bat];
  float gxg = (float)gxp[2 * GS + (size_t)ts0 * BATCH + bat];
  float gxo = (float)gxp[3 * GS + (size_t)ts0 * BATCH + bat];

  const bool i1 = (fk >> 1) & 1, i0 = fk & 1;
  const unsigned c64 = 0x64646464u;

  for (int t = 0; t < T_LEN; ++t) {
    // wave0 polls the 64-flag array (one lane per flag); others join at barrier
    if (w == 0) {
      const int want = t + 1;
      for (;;) {
        int v;
        asm volatile("global_load_dword %0, %1, off sc0 sc1\n\ts_waitcnt vmcnt(0)"
                     : "=&v"(v) : "v"(fl + lane) : "memory");
        if (__all(v >= want)) break;
        __builtin_amdgcn_s_sleep(1);
      }
    }
    barrier_lgkm();  // all WGs of this dir have published h(t-1)

    const unsigned char* src = (t & 1) ? buf1 : buf0;
    unsigned char* dst = (t & 1) ? buf0 : buf1;

    // stage h(t-1): 32KB u8 coherent load -> v_perm dequant -> swizzled LDS
    int4v u8v[4];
#pragma unroll
    for (int cc = 0; cc < 4; ++cc)
      u8v[cc] = load_co16(src + cc * 8192 + tid * 16);
    waitcnt0();
#pragma unroll
    for (int cc = 0; cc < 4; ++cc) {
      int b = cc * 8 + w;                 // (cc*8192 + tid*16)>>10
      int lslot = lane * 2;               // fp16 16B-slot index
      char* row = (char*)h_s + b * 2048;
      int swz = (b & 7) << 4;
      int4v A, B2;
      A[0]  = __builtin_amdgcn_perm(c64, (unsigned)u8v[cc][0], 0x05010400u);
      A[1]  = __builtin_amdgcn_perm(c64, (unsigned)u8v[cc][0], 0x07030602u);
      A[2]  = __builtin_amdgcn_perm(c64, (unsigned)u8v[cc][1], 0x05010400u);
      A[3]  = __builtin_amdgcn_perm(c64, (unsigned)u8v[cc][1], 0x07030602u);
      B2[0] = __builtin_amdgcn_perm(c64, (unsigned)u8v[cc][2], 0x05010400u);
      B2[1] = __builtin_amdgcn_perm(c64, (unsigned)u8v[cc][2], 0x07030602u);
      B2[2] = __builtin_amdgcn_perm(c64, (unsigned)u8v[cc][3], 0x05010400u);
      B2[3] = __builtin_amdgcn_perm(c64, (unsigned)u8v[cc][3], 0x07030602u);
      *(int4v*)(row + ((lslot * 16) ^ swz)) = A;
      *(int4v*)(row + (((lslot + 1) * 16) ^ swz)) = B2;
    }

    // prefetch gx(t+1): latency hides under MFMA + next poll
    int tn = (t + 1 < T_LEN) ? t + 1 : t;
    int tsn = dir ? (T_LEN - 1 - tn) : tn;
    float ngxi = (float)gxp[0 * GS + (size_t)tsn * BATCH + bat];
    float ngxf = (float)gxp[1 * GS + (size_t)tsn * BATCH + bat];
    float ngxg = (float)gxp[2 * GS + (size_t)tsn * BATCH + bat];
    float ngxo = (float)gxp[3 * GS + (size_t)tsn * BATCH + bat];

    barrier_lgkm();  // h_s ready (no vmcnt drain)

    // MFMA over B' = 1024+u8; 1152*rowsum offset folded into acc0 init
    floatx4 acc0 = {-corr0, -corr1, -corr2, -corr3};
    floatx4 acc1 = {0.f, 0.f, 0.f, 0.f};
    {
      const char* hp = (const char*)h_s + bat * 2048;
      const int bx = (bat & 7) << 4;
#pragma unroll
      for (int kt = 0; kt < 32; kt += 2) {
        half8 b0 = *(const half8*)(hp + ((kt * 64 + fk * 16) ^ bx));
        half8 b1 = *(const half8*)(hp + (((kt + 1) * 64 + fk * 16) ^ bx));
        acc0 = __builtin_amdgcn_mfma_f32_16x16x32_f16(af[kt], b0, acc0, 0, 0, 0);
        acc1 = __builtin_amdgcn_mfma_f32_16x16x32_f16(af[kt + 1], b1, acc1, 0, 0, 0);
      }
    }
    floatx4 v = acc0 + acc1;

    float gI, gF, gG, gO;
    gate_xpose(v, i1, i0, gI, gF, gG, gO);

    float ig = hsig(gI + gxi);
    float fg = hsig(gF + gxf);
    float gg = htanh(gG + gxg);
    float og = hsig(gO + gxo);
    c = fg * c + ig * gg;
    float h = og * htanh(c);

    // quantize + stage out
    {
      int q = (int)rintf(h * 127.f) + 128;   // h in [-1,1] by construction
      hout_s[bat * UPW + wu * 4 + fk] = (unsigned char)q;
    }

    const int tseq = dir ? (T_LEN - 1 - t) : t;
    size_t yidx = ((size_t)tseq * BATCH + bat) * 2048 + (size_t)dir * 1024 + unit;
    if (yf16) yf16[yidx] = (_Float16)h;
    else      yf32[yidx] = h;

    gxi = ngxi; gxf = ngxf; gxg = ngxg; gxo = ngxo;

    if (t == T_LEN - 1) {
      size_t o = st0 + (size_t)bat * HID + unit;
      hn[o] = h;
      cn[o] = c;
    } else {
      barrier_lgkm();  // hout_s ready; all h_s reads of this step done
      if (w == 0) {
        int b = lane >> 1, hf = lane & 1;
        int2v v2 = *(const int2v*)(hout_s + lane * 8);
        store_co8(dst + (size_t)b * HID + u0 + hf * 8, v2);
        waitcnt0();
        if (lane == 0) {
          int fv = t + 2;
          asm volatile("global_store_dword %0, %1, off sc0 sc1"
                       :: "v"(fl + wgd), "v"(fv) : "memory");
        }
      }
      // non-wave0 waves run ahead to the next top barrier
    }
  }
}

extern "C" void kernel_launch(void* const* d_in, const int* in_sizes, int n_in,
                              void* d_out, int out_size, void* d_ws, size_t ws_size,
                              hipStream_t stream) {
  const float* x    = (const float*)d_in[0];
  const float* h0   = (const float*)d_in[1];
  const float* c0   = (const float*)d_in[2];
  const float* wih0 = (const float*)d_in[3];
  const float* whh0 = (const float*)d_in[4];
  const float* b0   = (const float*)d_in[5];
  const float* wih1 = (const float*)d_in[6];
  const float* whh1 = (const float*)d_in[7];
  const float* b1   = (const float*)d_in[8];
  float* out = (float*)d_out;

  char* ws = (char*)d_ws;
  size_t off = 0;
  int* flags = (int*)ws;                          off += 4096;
  unsigned char* hbuf = (unsigned char*)(ws + off); off += 262144;
  _Float16* xh    = (_Float16*)(ws + off);    off += (size_t)8388608 * 2;
  _Float16* wih0h = (_Float16*)(ws + off);    off += (size_t)4194304 * 2;
  _Float16* whh0h = (_Float16*)(ws + off);    off += (size_t)8388608 * 2;
  _Float16* wih1h = (_Float16*)(ws + off);    off += (size_t)16777216 * 2;
  _Float16* whh1h = (_Float16*)(ws + off);    off += (size_t)8388608 * 2;
  _Float16* y0h   = (_Float16*)(ws + off);    off += (size_t)33554432 * 2;
  _Float16* gxbuf = (_Float16*)(ws + off);    off += (size_t)134217728 * 2;

  hipMemsetAsync(flags, 0, 4096, stream);

  cvt_f32_f16<<<2048, 256, 0, stream>>>(x,    xh,    8388608 / 4);
  cvt_f32_f16<<<2048, 256, 0, stream>>>(wih0, wih0h, 4194304 / 4);
  cvt_f32_f16<<<2048, 256, 0, stream>>>(whh0, whh0h, 8388608 / 4);
  cvt_f32_f16<<<2048, 256, 0, stream>>>(wih1, wih1h, 16777216 / 4);
  cvt_f32_f16<<<2048, 256, 0, stream>>>(whh1, whh1h, 8388608 / 4);

  float* hn = out + 33554432;
  float* cn = out + 33685504;

  // layer 0
  gemm_gx<<<8192, 256, 0, stream>>>(wih0h, xh, b0, gxbuf, 512);
  recur<<<128, 512, 0, stream>>>(gxbuf, whh0h, h0, c0, hbuf, flags, 0,
                                 y0h, nullptr, hn, cn);
  // layer 1
  gemm_gx<<<8192, 256, 0, stream>>>(wih1h, y0h, b1, gxbuf, 2048);
  recur<<<128, 512, 0, stream>>>(gxbuf, whh1h, h0, c0, hbuf + 131072, flags + 128, 1,
                                 nullptr, out, hn, cn);
}

// Round 9
// 5719.338 us; speedup vs baseline: 2.7796x; 1.0519x over previous
//
#include <hip/hip_runtime.h>
#include <cstdint>

// HardLSTM: T=512 B=32 I=512 H=1024, 2 layers, bidirectional.
// cvt(fp32->fp16) -> GEMM gx0 -> persistent recur L0 -> GEMM gx1 -> recur L1.
// Recurrence (r5/r8 protocol): u8 h via sc0|sc1 (coherent-at-L3), per-WG flag
// array, wave0 polls, lgkm-only barriers, gx prefetch, v_perm dequant
// (B' = 1024+u8, weights pre-scaled 1/127, 1152*rowsum folded into acc init).
// NEW r9: 32 WGs/dir x 32 units (fewer producers: less straggle/contention);
// per-wave direct publish (shfl-pack -> dword stores) right after elementwise;
// y-stores AFTER the flag (HBM drain off the ack path); poll backoff; staggered
// stage addressing.

typedef _Float16 half8 __attribute__((ext_vector_type(8)));
typedef _Float16 half4v __attribute__((ext_vector_type(4)));
typedef float floatx4 __attribute__((ext_vector_type(4)));
typedef int int4v __attribute__((ext_vector_type(4)));

#define T_LEN 512
#define BATCH 32
#define HID 1024
#define NTB 16384   // T*B
#define UPW 32      // hidden units per WG
#define WPD 32      // WGs per direction

__device__ __forceinline__ float hsig(float x) {
  return fminf(fmaxf(fmaf(0.2f, x, 0.5f), 0.0f), 1.0f);
}
__device__ __forceinline__ float htanh(float x) {
  return fminf(fmaxf(x, -1.0f), 1.0f);
}

__device__ __forceinline__ int4v load_co16(const void* p) {
  int4v r;
  asm volatile("global_load_dwordx4 %0, %1, off sc0 sc1"
               : "=&v"(r) : "v"(p) : "memory");
  return r;
}
__device__ __forceinline__ void store_co4(void* p, int v) {
  asm volatile("global_store_dword %0, %1, off sc0 sc1"
               :: "v"(p), "v"(v) : "memory");
}
__device__ __forceinline__ void waitcnt0() {
  asm volatile("s_waitcnt vmcnt(0)" ::: "memory");
}
// barrier with LDS-visibility only (no vmcnt drain)
__device__ __forceinline__ void barrier_lgkm() {
  asm volatile("s_waitcnt lgkmcnt(0)" ::: "memory");
  __builtin_amdgcn_sched_barrier(0);
  __builtin_amdgcn_s_barrier();
  __builtin_amdgcn_sched_barrier(0);
}

__device__ __forceinline__ void gll16(const void* g, void* l) {
  __builtin_amdgcn_global_load_lds((const __attribute__((address_space(1))) void*)g,
                                   (__attribute__((address_space(3))) void*)l,
                                   16, 0, 0);
}

// 4x4 transpose across fk lane-groups (proven r3/r5/r8)
__device__ __forceinline__ void gate_xpose(floatx4 v, bool i1, bool i0,
                                           float& gI, float& gF,
                                           float& gG, float& gO) {
  float s0 = i1 ? v[0] : v[2], s1 = i1 ? v[1] : v[3];
  float r0 = __shfl_xor(s0, 32), r1 = __shfl_xor(s1, 32);
  float A0 = i1 ? r0 : v[0], A1 = i1 ? r1 : v[1];
  float A2 = i1 ? v[2] : r0, A3 = i1 ? v[3] : r1;
  s0 = i0 ? A0 : A1; s1 = i0 ? A2 : A3;
  r0 = __shfl_xor(s0, 16); r1 = __shfl_xor(s1, 16);
  gI = i0 ? r0 : A0; gF = i0 ? A1 : r0;
  gG = i0 ? r1 : A2; gO = i0 ? A3 : r1;
}

// pack 4 fk-lanes' u8 (this lane: value q for unit u0+w*4+fk) into a dword on
// fk==0 lanes: byte j = q(fk=j). 2 shfl_xor. (r6's publish_h pattern, proven)
__device__ __forceinline__ int pack_u8_fk(int q, int fk) {
  int p = __shfl_xor(q, 16);
  int d = (fk & 1) ? ((p & 0xff) | ((q & 0xff) << 8))
                   : ((q & 0xff) | ((p & 0xff) << 8));
  int d2 = __shfl_xor(d, 32);
  return (d & 0xffff) | (d2 << 16);
}

__global__ __launch_bounds__(256) void cvt_f32_f16(const float* __restrict__ s,
                                                   _Float16* __restrict__ d,
                                                   int n4) {
  int i = blockIdx.x * blockDim.x + threadIdx.x;
  int stride = gridDim.x * blockDim.x;
  for (; i < n4; i += stride) {
    float4 v = ((const float4*)s)[i];
    half4v h = {(_Float16)v.x, (_Float16)v.y, (_Float16)v.z, (_Float16)v.w};
    ((half4v*)d)[i] = h;
  }
}

// C[M=8192][NTB] = A[M][K] * B[NTB][K]^T + bias[M], fp16 out. (unchanged)
__global__ __launch_bounds__(256) void gemm_gx(const _Float16* __restrict__ A,
                                               const _Float16* __restrict__ B,
                                               const float* __restrict__ bias,
                                               _Float16* __restrict__ C,
                                               int K) {
  __shared__ __align__(16) _Float16 A_s[128 * 64];
  __shared__ __align__(16) _Float16 B_s[128 * 64];
  const int tid = threadIdx.x;
  const int lane = tid & 63;
  const int w = tid >> 6;
  const int bm = blockIdx.x >> 7;
  const int bn = blockIdx.x & 127;
  const int m0 = bm * 128, n0 = bn * 128;

  floatx4 acc[4][4] = {};

  const int srow = w * 8 + (lane >> 3);
  const int scol = ((lane & 7) ^ ((lane >> 3) & 7)) * 8;
  const _Float16* Ag = A + (size_t)(m0 + srow) * K + scol;
  const _Float16* Bg = B + (size_t)(n0 + srow) * K + scol;
  char* As_base = (char*)A_s + (size_t)(w * 8) * 128;
  char* Bs_base = (char*)B_s + (size_t)(w * 8) * 128;

  const int wm = (w >> 1) * 64;
  const int wn = (w & 1) * 64;
  const int fr = lane & 15;
  const int fk = lane >> 4;

  for (int kb = 0; kb < K; kb += 64) {
#pragma unroll
    for (int i = 0; i < 4; ++i) {
      gll16(Ag + (size_t)i * 32 * K + kb, As_base + i * 32 * 128);
      gll16(Bg + (size_t)i * 32 * K + kb, Bs_base + i * 32 * 128);
    }
    __syncthreads();
#pragma unroll
    for (int kt = 0; kt < 2; ++kt) {
      half8 af[4], bf[4];
#pragma unroll
      for (int mi = 0; mi < 4; ++mi) {
        int row = wm + mi * 16 + fr;
        int k8 = kt * 4 + fk;
        af[mi] = *(const half8*)(A_s + row * 64 + ((k8 ^ (row & 7)) << 3));
      }
#pragma unroll
      for (int ni = 0; ni < 4; ++ni) {
        int row = wn + ni * 16 + fr;
        int k8 = kt * 4 + fk;
        bf[ni] = *(const half8*)(B_s + row * 64 + ((k8 ^ (row & 7)) << 3));
      }
#pragma unroll
      for (int mi = 0; mi < 4; ++mi)
#pragma unroll
        for (int ni = 0; ni < 4; ++ni)
          acc[mi][ni] = __builtin_amdgcn_mfma_f32_16x16x32_f16(af[mi], bf[ni],
                                                               acc[mi][ni], 0, 0, 0);
    }
    __syncthreads();
  }

#pragma unroll
  for (int mi = 0; mi < 4; ++mi) {
    int rowb = m0 + wm + mi * 16 + fk * 4;
#pragma unroll
    for (int r = 0; r < 4; ++r) {
      float bv = bias[rowb + r];
#pragma unroll
      for (int ni = 0; ni < 4; ++ni) {
        int col = n0 + wn + ni * 16 + fr;
        C[(size_t)(rowb + r) * NTB + col] = (_Float16)(acc[mi][ni][r] + bv);
      }
    }
  }
}

// Persistent bidirectional recurrence. Grid = 64 WGs x 512 thr.
// Wave w owns 16 gate rows = 4 gates x 4 units (units u0+w*4+du), BOTH batch
// halves. Lane (fk,fr): A row fr -> gate fr>>2, du fr&3. Post-xpose lane owns
// unit u0+w*4+fk, batches fr and 16+fr.
__global__ __launch_bounds__(512, 2) void recur(const _Float16* __restrict__ gx,
                                                const _Float16* __restrict__ whh,
                                                const float* __restrict__ h0,
                                                const float* __restrict__ c0,
                                                unsigned char* __restrict__ hbuf,
                                                int* __restrict__ flags,
                                                int layer,
                                                _Float16* __restrict__ yf16,
                                                float* __restrict__ yf32,
                                                float* __restrict__ hn,
                                                float* __restrict__ cn) {
  __shared__ __align__(16) _Float16 h_s[BATCH * HID];  // 64KB swizzled [b][k]

  const int tid = threadIdx.x;
  const int lane = tid & 63;
  const int w = tid >> 6;
  const int dir = blockIdx.x >> 5;
  const int wgd = blockIdx.x & 31;
  const int u0 = wgd * UPW;
  const int fr = lane & 15, fk = lane >> 4;

  // A fragments scaled by 1/127; rowsum for the 1152-offset correction.
  half8 af[32];
  float rowsum = 0.f;
  {
    const int g = fr >> 2, du = fr & 3;
    const _Float16* wrow = whh + ((size_t)dir * 4096 + g * 1024 + u0 + w * 4 + du) * HID;
#pragma unroll
    for (int kt = 0; kt < 32; ++kt) {
      half8 raw = *(const half8*)(wrow + kt * 32 + fk * 8);
      half8 s;
#pragma unroll
      for (int e = 0; e < 8; ++e) {
        float v = (float)raw[e] * (1.f / 127.f);
        s[e] = (_Float16)v;
        rowsum += (float)s[e];
      }
      af[kt] = s;
    }
  }
  rowsum += __shfl_xor(rowsum, 16);
  rowsum += __shfl_xor(rowsum, 32);     // rowsum(row fr) on all lanes
  float corr0 = 1152.f * __shfl(rowsum, fk * 4 + 0);
  float corr1 = 1152.f * __shfl(rowsum, fk * 4 + 1);
  float corr2 = 1152.f * __shfl(rowsum, fk * 4 + 2);
  float corr3 = 1152.f * __shfl(rowsum, fk * 4 + 3);

  const int unit = u0 + w * 4 + fk;    // this lane's unit (post-transpose)
  const int batA = fr, batB = 16 + fr;
  const size_t st0 = (size_t)(layer * 2 + dir) * (BATCH * HID);
  float cA = c0[st0 + (size_t)batA * HID + unit];
  float cB = c0[st0 + (size_t)batB * HID + unit];

  unsigned char* buf0 = hbuf + (size_t)dir * 32768;
  unsigned char* buf1 = hbuf + (size_t)(2 + dir) * 32768;
  int* fl = flags + dir * WPD;

  // init: quantize h0, per-wave pack+publish into parity-0, flag=1
  {
    float hA0 = h0[st0 + (size_t)batA * HID + unit];
    float hB0 = h0[st0 + (size_t)batB * HID + unit];
    int qA = (int)rintf(fminf(fmaxf(hA0, -1.f), 1.f) * 127.f) + 128;
    int qB = (int)rintf(fminf(fmaxf(hB0, -1.f), 1.f) * 127.f) + 128;
    int dwA = pack_u8_fk(qA, fk);
    int dwB = pack_u8_fk(qB, fk);
    if (fk == 0) {
      store_co4(buf0 + (size_t)batA * HID + u0 + w * 4, dwA);
      store_co4(buf0 + (size_t)batB * HID + u0 + w * 4, dwB);
    }
    waitcnt0();
    barrier_lgkm();
    if (tid == 0) store_co4(fl + wgd, 1);
  }

  const size_t GS = (size_t)1024 * NTB;
  const _Float16* gxp = gx + ((size_t)dir * 4096 + unit) * NTB;

  // preload gx for t=0
  int ts0 = dir ? (T_LEN - 1) : 0;
  float gxiA = (float)gxp[0 * GS + (size_t)ts0 * BATCH + batA];
  float gxfA = (float)gxp[1 * GS + (size_t)ts0 * BATCH + batA];
  float gxgA = (float)gxp[2 * GS + (size_t)ts0 * BATCH + batA];
  float gxoA = (float)gxp[3 * GS + (size_t)ts0 * BATCH + batA];
  float gxiB = (float)gxp[0 * GS + (size_t)ts0 * BATCH + batB];
  float gxfB = (float)gxp[1 * GS + (size_t)ts0 * BATCH + batB];
  float gxgB = (float)gxp[2 * GS + (size_t)ts0 * BATCH + batB];
  float gxoB = (float)gxp[3 * GS + (size_t)ts0 * BATCH + batB];

  const bool i1 = (fk >> 1) & 1, i0 = fk & 1;
  const unsigned c64 = 0x64646464u;
  const int e = (tid + wgd * 8) & 511;   // staggered stage index
  const int eb = e >> 6, el = e & 63;    // sub-block, lane-slot within 1KB row

  for (int t = 0; t < T_LEN; ++t) {
    // wave0 polls the flag array; others join at barrier
    if (w == 0) {
      const int want = t + 1;
      for (;;) {
        int v;
        asm volatile("global_load_dword %0, %1, off sc0 sc1\n\ts_waitcnt vmcnt(0)"
                     : "=&v"(v) : "v"(fl + (lane & 31)) : "memory");
        if (__all(v >= want)) break;
        __builtin_amdgcn_s_sleep(2);
      }
    }
    barrier_lgkm();  // all WGs of this dir have published h(t-1)

    const unsigned char* src = (t & 1) ? buf1 : buf0;
    unsigned char* dst = (t & 1) ? buf0 : buf1;

    // stage h(t-1): 32KB u8 coherent load (staggered) -> v_perm dequant -> LDS
    int4v u8v[4];
#pragma unroll
    for (int cc = 0; cc < 4; ++cc)
      u8v[cc] = load_co16(src + cc * 8192 + e * 16);
    waitcnt0();
#pragma unroll
    for (int cc = 0; cc < 4; ++cc) {
      int b = cc * 8 + eb;                // LDS batch row
      int lslot = el * 2;                 // fp16 16B-slot index
      char* row = (char*)h_s + b * 2048;
      int swz = (b & 7) << 4;
      int4v A, B2;
      A[0]  = __builtin_amdgcn_perm(c64, (unsigned)u8v[cc][0], 0x05010400u);
      A[1]  = __builtin_amdgcn_perm(c64, (unsigned)u8v[cc][0], 0x07030602u);
      A[2]  = __builtin_amdgcn_perm(c64, (unsigned)u8v[cc][1], 0x05010400u);
      A[3]  = __builtin_amdgcn_perm(c64, (unsigned)u8v[cc][1], 0x07030602u);
      B2[0] = __builtin_amdgcn_perm(c64, (unsigned)u8v[cc][2], 0x05010400u);
      B2[1] = __builtin_amdgcn_perm(c64, (unsigned)u8v[cc][2], 0x07030602u);
      B2[2] = __builtin_amdgcn_perm(c64, (unsigned)u8v[cc][3], 0x05010400u);
      B2[3] = __builtin_amdgcn_perm(c64, (unsigned)u8v[cc][3], 0x07030602u);
      *(int4v*)(row + ((lslot * 16) ^ swz)) = A;
      *(int4v*)(row + (((lslot + 1) * 16) ^ swz)) = B2;
    }

    // prefetch gx(t+1)
    int tn = (t + 1 < T_LEN) ? t + 1 : t;
    int tsn = dir ? (T_LEN - 1 - tn) : tn;
    float ngxiA = (float)gxp[0 * GS + (size_t)tsn * BATCH + batA];
    float ngxfA = (float)gxp[1 * GS + (size_t)tsn * BATCH + batA];
    float ngxgA = (float)gxp[2 * GS + (size_t)tsn * BATCH + batA];
    float ngxoA = (float)gxp[3 * GS + (size_t)tsn * BATCH + batA];
    float ngxiB = (float)gxp[0 * GS + (size_t)tsn * BATCH + batB];
    float ngxfB = (float)gxp[1 * GS + (size_t)tsn * BATCH + batB];
    float ngxgB = (float)gxp[2 * GS + (size_t)tsn * BATCH + batB];
    float ngxoB = (float)gxp[3 * GS + (size_t)tsn * BATCH + batB];

    barrier_lgkm();  // h_s ready (no vmcnt drain)

    // MFMA over B' = 1024+u8; corr folded into chain-0 inits
    floatx4 aA0 = {-corr0, -corr1, -corr2, -corr3};
    floatx4 aB0 = {-corr0, -corr1, -corr2, -corr3};
    floatx4 aA1 = {0.f, 0.f, 0.f, 0.f}, aB1 = {0.f, 0.f, 0.f, 0.f};
    {
      const char* hpA = (const char*)h_s + batA * 2048;
      const char* hpB = (const char*)h_s + batB * 2048;
      const int bxA = (batA & 7) << 4;
      const int bxB = (batB & 7) << 4;
#pragma unroll
      for (int kt = 0; kt < 32; kt += 2) {
        half8 b0A = *(const half8*)(hpA + ((kt * 64 + fk * 16) ^ bxA));
        half8 b0B = *(const half8*)(hpB + ((kt * 64 + fk * 16) ^ bxB));
        half8 b1A = *(const half8*)(hpA + (((kt + 1) * 64 + fk * 16) ^ bxA));
        half8 b1B = *(const half8*)(hpB + (((kt + 1) * 64 + fk * 16) ^ bxB));
        aA0 = __builtin_amdgcn_mfma_f32_16x16x32_f16(af[kt], b0A, aA0, 0, 0, 0);
        aB0 = __builtin_amdgcn_mfma_f32_16x16x32_f16(af[kt], b0B, aB0, 0, 0, 0);
        aA1 = __builtin_amdgcn_mfma_f32_16x16x32_f16(af[kt + 1], b1A, aA1, 0, 0, 0);
        aB1 = __builtin_amdgcn_mfma_f32_16x16x32_f16(af[kt + 1], b1B, aB1, 0, 0, 0);
      }
    }
    floatx4 vA = aA0 + aA1, vB = aB0 + aB1;

    float gI, gF, gG, gO;
    gate_xpose(vA, i1, i0, gI, gF, gG, gO);
    float igA = hsig(gI + gxiA);
    float fgA = hsig(gF + gxfA);
    float ggA = htanh(gG + gxgA);
    float ogA = hsig(gO + gxoA);
    cA = fgA * cA + igA * ggA;
    float hA = ogA * htanh(cA);

    gate_xpose(vB, i1, i0, gI, gF, gG, gO);
    float igB = hsig(gI + gxiB);
    float fgB = hsig(gF + gxfB);
    float ggB = htanh(gG + gxgB);
    float ogB = hsig(gO + gxoB);
    cB = fgB * cB + igB * ggB;
    float hB = ogB * htanh(cB);

    gxiA = ngxiA; gxfA = ngxfA; gxgA = ngxgA; gxoA = ngxoA;
    gxiB = ngxiB; gxfB = ngxfB; gxgB = ngxgB; gxoB = ngxoB;

    const int tseq = dir ? (T_LEN - 1 - t) : t;

    if (t == T_LEN - 1) {
      size_t oA = st0 + (size_t)batA * HID + unit;
      size_t oB = st0 + (size_t)batB * HID + unit;
      hn[oA] = hA; cn[oA] = cA;
      hn[oB] = hB; cn[oB] = cB;
    } else {
      // PUBLISH FIRST (critical path): pack u8, per-wave dword stores, ack,
      // barrier, flag. y-stores come after the flag.
      int qA = (int)rintf(hA * 127.f) + 128;   // h in [-1,1] by construction
      int qB = (int)rintf(hB * 127.f) + 128;
      int dwA = pack_u8_fk(qA, fk);
      int dwB = pack_u8_fk(qB, fk);
      if (fk == 0) {
        store_co4(dst + (size_t)batA * HID + u0 + w * 4, dwA);
        store_co4(dst + (size_t)batB * HID + u0 + w * 4, dwB);
      }
      waitcnt0();       // own publish acked at coherence point
      barrier_lgkm();   // all waves' publishes acked; h_s reads also done
      if (tid == 0) store_co4(fl + wgd, t + 2);
    }

    // y output (off the critical path; drains during next poll window)
    size_t yA = ((size_t)tseq * BATCH + batA) * 2048 + (size_t)dir * 1024 + unit;
    size_t yB = ((size_t)tseq * BATCH + batB) * 2048 + (size_t)dir * 1024 + unit;
    if (yf16) { yf16[yA] = (_Float16)hA; yf16[yB] = (_Float16)hB; }
    else      { yf32[yA] = hA;           yf32[yB] = hB; }

    if (t == T_LEN - 1) {
      // nothing further
    }
  }
}

extern "C" void kernel_launch(void* const* d_in, const int* in_sizes, int n_in,
                              void* d_out, int out_size, void* d_ws, size_t ws_size,
                              hipStream_t stream) {
  const float* x    = (const float*)d_in[0];
  const float* h0   = (const float*)d_in[1];
  const float* c0   = (const float*)d_in[2];
  const float* wih0 = (const float*)d_in[3];
  const float* whh0 = (const float*)d_in[4];
  const float* b0   = (const float*)d_in[5];
  const float* wih1 = (const float*)d_in[6];
  const float* whh1 = (const float*)d_in[7];
  const float* b1   = (const float*)d_in[8];
  float* out = (float*)d_out;

  char* ws = (char*)d_ws;
  size_t off = 0;
  int* flags = (int*)ws;                          off += 4096;
  unsigned char* hbuf = (unsigned char*)(ws + off); off += 262144;
  _Float16* xh    = (_Float16*)(ws + off);    off += (size_t)8388608 * 2;
  _Float16* wih0h = (_Float16*)(ws + off);    off += (size_t)4194304 * 2;
  _Float16* whh0h = (_Float16*)(ws + off);    off += (size_t)8388608 * 2;
  _Float16* wih1h = (_Float16*)(ws + off);    off += (size_t)16777216 * 2;
  _Float16* whh1h = (_Float16*)(ws + off);    off += (size_t)8388608 * 2;
  _Float16* y0h   = (_Float16*)(ws + off);    off += (size_t)33554432 * 2;
  _Float16* gxbuf = (_Float16*)(ws + off);    off += (size_t)134217728 * 2;

  hipMemsetAsync(flags, 0, 4096, stream);

  cvt_f32_f16<<<2048, 256, 0, stream>>>(x,    xh,    8388608 / 4);
  cvt_f32_f16<<<2048, 256, 0, stream>>>(wih0, wih0h, 4194304 / 4);
  cvt_f32_f16<<<2048, 256, 0, stream>>>(whh0, whh0h, 8388608 / 4);
  cvt_f32_f16<<<2048, 256, 0, stream>>>(wih1, wih1h, 16777216 / 4);
  cvt_f32_f16<<<2048, 256, 0, stream>>>(whh1, whh1h, 8388608 / 4);

  float* hn = out + 33554432;
  float* cn = out + 33685504;

  // layer 0
  gemm_gx<<<8192, 256, 0, stream>>>(wih0h, xh, b0, gxbuf, 512);
  recur<<<64, 512, 0, stream>>>(gxbuf, whh0h, h0, c0, hbuf, flags, 0,
                                y0h, nullptr, hn, cn);
  // layer 1
  gemm_gx<<<8192, 256, 0, stream>>>(wih1h, y0h, b1, gxbuf, 2048);
  recur<<<64, 512, 0, stream>>>(gxbuf, whh1h, h0, c0, hbuf + 131072, flags + 128, 1,
                                nullptr, out, hn, cn);
}